// Round 10
// baseline (451.505 us; speedup 1.0000x reference)
//
#include <hip/hip_runtime.h>
#include <math.h>

namespace {

typedef unsigned short ushort_t;
typedef unsigned int uint_t;
typedef unsigned char uchar_t;
typedef __attribute__((ext_vector_type(4))) float f32x4;

constexpr int NBATCH = 16;
constexpr int NCH    = 21;
constexpr int HH     = 41;
constexpr int NP     = HH * HH;       // 1681 pixels
constexpr int IW     = 321;           // input image H=W
constexpr int QS     = 32;            // padded channel stride for P/LOGU/QF
constexpr float EPSV = 1e-5f;

constexpr int NKB    = 56;            // K blocks of 32 (53 live + 3 zero-B pads)
constexpr int NTILE  = 106;           // 16-row tiles per batch
constexpr int NPAIR  = 53;            // 32-row pairs per batch
constexpr int NPIX   = NBATCH * NP;             // 26896
constexpr int LOSS_BLOCKS = (NPIX + 255) / 256; // 106
constexpr int RSB_TILES = (NP + 63) / 64;       // 27
constexpr int BMROWS = 8;
constexpr int BMTILES = (NP + BMROWS - 1) / BMROWS;   // 211

// A-fragment-linear M: [nb][tile][kb][lane][8B]
constexpr size_t M_TILE  = (size_t)NKB * 512;           // 28672 B
constexpr size_t M_BATCH = (size_t)NTILE * M_TILE;      // 3,039,232 B

// B-fragment-linear Q storage (fp8): per batch [56 kb][2 ct][64 lane][8 B]
constexpr int QB_BATCH = NKB * 2 * 512;          // 57344 bytes per batch
constexpr int QB_BUF   = NBATCH * QB_BATCH;      // 917504 bytes per buffer
constexpr int RXN = NBATCH * 3 * IW * HH;        // 631728

constexpr float CS_COLOR = 0.06533245f;   // sqrt(log2(e)/338)
constexpr float CS_XY    = 0.12739827f;   // sqrt(0.01125*log2(e))
constexpr float L2E8     = 11.5415603f;   // 8*log2(e)
constexpr float HLOG2_10 = 1.6609640474f; // 0.5*log2(10)

// workspace offsets in floats
constexpr size_t OFF_W    = 0;                   // 13184
constexpr size_t OFF_RX   = 13184;               // 631744
constexpr size_t OFF_COL  = 644928;              // scaled colors + log-weight w [npix][4]
constexpr size_t OFF_P    = 752512;              // 860672
constexpr size_t OFF_LOGU = 1613184;             // 860672
constexpr size_t OFF_QF   = 2473856;             // 860672
constexpr size_t OFF_RSG  = 3334528;             // 1728
constexpr size_t OFF_XY   = 3336256;             // 3456
constexpr size_t OFF_PART = 3339712;             // 256
constexpr size_t OFF_QB   = 3339968;             // 2 fp8 buffers = 458752 floats
constexpr size_t OFF_M    = 3798720;             // fp8 M frag [16][106][56][64][8]
constexpr size_t OFF_PJ   = 15955648;            // PJ [npix][8] = 215168 floats
// total ~64.7 MB (ws proven >= ~195 MB in round 1)

constexpr size_t QB_ZERO_DWORDS = 458752;        // both QB buffers, dwords

__device__ __forceinline__ float wave_sum(float v) {
  #pragma unroll
  for (int off = 32; off > 0; off >>= 1) v += __shfl_down(v, off, 64);
  return v;
}

__device__ __forceinline__ uchar_t f32_to_fp8(float f) {
  return (uchar_t)(__builtin_amdgcn_cvt_pk_fp8_f32(f, f, 0, false) & 0xff);
}

__global__ void k_zero(uint_t* __restrict__ p) {
  size_t t = (size_t)blockIdx.x * blockDim.x + threadIdx.x;
  if (t < QB_ZERO_DWORDS) p[t] = 0u;
}

// K1: jax.image.resize 'linear' (antialias) weight matrix, 321 -> 41.
__global__ void k_weights(float* __restrict__ W) {
  int o = threadIdx.x;
  if (o >= HH) return;
  const float inv = (float)IW / (float)HH;
  float s = (o + 0.5f) * inv - 0.5f;
  float tot = 0.f;
  for (int i = 0; i < IW; ++i) {
    float x = fabsf(s - (float)i) / inv;
    tot += fmaxf(0.f, 1.f - x);
  }
  float r = 1.f / tot;
  for (int i = 0; i < IW; ++i) {
    float x = fabsf(s - (float)i) / inv;
    W[o * IW + i] = fmaxf(0.f, 1.f - x) * r;
  }
}

__global__ void k_xy(float2* __restrict__ XY) {
  int j = blockIdx.x * blockDim.x + threadIdx.x;
  if (j >= NP) return;
  XY[j] = make_float2((float)(j % HH) * CS_XY, (float)(j / HH) * CS_XY);
}

// K2a: separable resize, x pass
__global__ void k_resize_x(const float* __restrict__ img, const float* __restrict__ W,
                           float* __restrict__ RX) {
  int t = blockIdx.x * blockDim.x + threadIdx.x;
  if (t >= RXN) return;
  int xo = t % HH;
  int rest = t / HH;
  int y = rest % IW;
  int nc = rest / IW;
  const float inv = (float)IW / (float)HH;
  float sx = (xo + 0.5f) * inv - 0.5f;
  int xlo = max(0, (int)ceilf(sx - inv)), xhi = min(IW - 1, (int)floorf(sx + inv));
  const float* base = img + ((size_t)nc * IW + y) * IW;
  const float* wr = W + xo * IW;
  float a = 0.f;
  for (int ix = xlo; ix <= xhi; ++ix) a += wr[ix] * base[ix];
  RX[t] = a;
}

// K2b: y pass -> SCALED colors [n][p][4] (w filled later by k_rsb)
__global__ void k_resize_y(const float* __restrict__ RX, const float* __restrict__ W,
                           float* __restrict__ colors) {
  int t = blockIdx.x * blockDim.x + threadIdx.x;
  if (t >= NPIX) return;
  int nb = t / NP, p = t % NP;
  int yo = p / HH, xo = p % HH;
  const float inv = (float)IW / (float)HH;
  float sy = (yo + 0.5f) * inv - 0.5f;
  int ylo = max(0, (int)ceilf(sy - inv)), yhi = min(IW - 1, (int)floorf(sy + inv));
  const float* wr = W + yo * IW;
  float a0 = 0.f, a1 = 0.f, a2 = 0.f;
  const float* b0 = RX + (size_t)(nb * 3 + 0) * IW * HH + xo;
  const float* b1 = RX + (size_t)(nb * 3 + 1) * IW * HH + xo;
  const float* b2 = RX + (size_t)(nb * 3 + 2) * IW * HH + xo;
  for (int iy = ylo; iy <= yhi; ++iy) {
    float wy = wr[iy];
    a0 += wy * b0[(size_t)iy * HH];
    a1 += wy * b1[(size_t)iy * HH];
    a2 += wy * b2[(size_t)iy * HH];
  }
  float* c = colors + (size_t)t * 4;
  c[0] = a0 * CS_COLOR; c[1] = a1 * CS_COLOR; c[2] = a2 * CS_COLOR; c[3] = 0.f;
}

// K3: clamped channel softmax -> P, LOGU, initial fp8 B-fragments
__global__ void k_probs(const float* __restrict__ pred, float* __restrict__ P,
                        float* __restrict__ LOGU, uchar_t* __restrict__ QB) {
  int t = blockIdx.x * blockDim.x + threadIdx.x;
  if (t >= NPIX) return;
  int nb = t / NP, i = t % NP;
  const float* src = pred + (size_t)nb * NCH * NP + i;
  float v[NCH];
  float m = -1e30f;
  #pragma unroll
  for (int c = 0; c < NCH; ++c) { v[c] = src[(size_t)c * NP]; m = fmaxf(m, v[c]); }
  float s = 0.f;
  #pragma unroll
  for (int c = 0; c < NCH; ++c) { v[c] = expf(v[c] - m); s += v[c]; }
  float r = 1.f / s;
  float s2 = 0.f;
  #pragma unroll
  for (int c = 0; c < NCH; ++c) { v[c] = fminf(fmaxf(v[c] * r, EPSV), 1.0f); s2 += v[c]; }
  float r2 = 1.f / s2;
  float* dp = P + (size_t)t * QS;
  float* dl = LOGU + (size_t)t * QS;
  int kb = i >> 5, kr = i & 31, q2 = kr >> 3, j = kr & 7;
  size_t sb = (size_t)nb * QB_BATCH + (size_t)kb * 1024 + j;
  #pragma unroll
  for (int c = 0; c < NCH; ++c) {
    float p = v[c] * r2;
    dp[c] = p; dl[c] = logf(p);
    int ct = c >> 4;
    QB[sb + (size_t)ct * 512 + (q2 * 16 + (c & 15)) * 8] = f32_to_fp8(p);
  }
}

// K4: Gaussian row sums: rsg[i] = 1/sqrt(sum_{j!=i} exp(-8*d2))
__global__ void k_rsg(float* __restrict__ rsg) {
  int i = blockIdx.x;
  int lane = threadIdx.x;
  int xi = i % HH, yi = i / HH;
  float s = 0.f;
  for (int j = lane; j < NP; j += 64) {
    if (j == i) continue;
    int xj = j % HH, yj = j / HH;
    float dx = (float)(xi - xj), dy = (float)(yi - yj);
    s += __builtin_amdgcn_exp2f(-L2E8 * (dx * dx + dy * dy));
  }
  s = wave_sum(s);
  if (lane == 0) rsg[i] = 1.f / sqrtf(s);
}

// K5: bilateral row sums -> COL.w = log2(sqrt(10)*rsb_i)  (LDS-tiled)
__global__ __launch_bounds__(512) void k_rsb(float4* __restrict__ COL,
                                             const float2* __restrict__ XY) {
  __shared__ float S8[NP * 8];
  __shared__ float Red2[8 * 64];
  const int nb = blockIdx.x / RSB_TILES;
  const int i0 = (blockIdx.x % RSB_TILES) * 64;
  const int tid = (int)threadIdx.x;
  const int lane = tid & 63, wv = tid >> 6;

  const float4* colb = COL + (size_t)nb * NP;
  for (int j = tid; j < NP; j += 512) {
    float4 c = colb[j];
    float2 xy = XY[j];
    *(float4*)&S8[j * 8]     = make_float4(c.x, c.y, c.z, 0.f);
    *(float4*)&S8[j * 8 + 4] = make_float4(xy.x, xy.y, 0.f, 0.f);
  }
  __syncthreads();

  const int i = i0 + lane;
  const int im = min(i, NP - 1);
  const float ci0 = S8[im * 8], ci1 = S8[im * 8 + 1], ci2 = S8[im * 8 + 2];
  const float xi = S8[im * 8 + 4], yi = S8[im * 8 + 5];

  float s = 0.f;
  for (int j = wv; j < NP; j += 8) {
    float4 a = *(const float4*)&S8[j * 8];
    float4 b = *(const float4*)&S8[j * 8 + 4];
    float dx = xi - b.x, dy = yi - b.y;
    float acc = dx * dx;
    acc = fmaf(dy, dy, acc);
    float e0 = ci0 - a.x, e1 = ci1 - a.y, e2 = ci2 - a.z;
    acc = fmaf(e0, e0, acc);
    acc = fmaf(e1, e1, acc);
    acc = fmaf(e2, e2, acc);
    s += __builtin_amdgcn_exp2f(-acc);
  }
  Red2[wv * 64 + lane] = s;
  __syncthreads();
  if (wv == 0 && i < NP) {
    float t = -1.0f;   // remove self term
    #pragma unroll
    for (int w = 0; w < 8; ++w) t += Red2[w * 64 + lane];
    ((float*)(COL + (size_t)nb * NP + i))[3] = HLOG2_10 - 0.5f * __builtin_amdgcn_logf(t);
  }
}

// K5b: PJ[t] = {x, y, c0, c1, c2, A = w - |p|^2, 0, 0} — dot-product form support
__global__ void k_prep(const float4* __restrict__ COL, const float2* __restrict__ XY,
                       float* __restrict__ PJ) {
  int t = blockIdx.x * blockDim.x + threadIdx.x;
  if (t >= NPIX) return;
  float4 c = COL[t];
  float2 xy = XY[t % NP];
  float n2 = xy.x * xy.x + xy.y * xy.y + c.x * c.x + c.y * c.y + c.z * c.z;
  float* d = PJ + (size_t)t * 8;
  d[0] = xy.x; d[1] = xy.y; d[2] = c.x; d[3] = c.y; d[4] = c.z; d[5] = c.w - n2;
  d[6] = 0.f; d[7] = 0.f;
}

// K6: fp8 M in A-fragment-linear layout. Dot-product form:
// log2(val) = Ai + Aj + 2*(pi . pj). 8-row register tile, 8-j chunks,
// register-buffered wrd[8] -> 4 x 16B coalesced stores (no sector waste).
// Gaussian added exactly on 5x5 fixup pass. kb 53..55 / rows >= NP unwritten.
__global__ __launch_bounds__(256) void k_buildM(const float* __restrict__ PJ,
                                                const float* __restrict__ rsg,
                                                uchar_t* __restrict__ M) {
  const int nb = blockIdx.x / BMTILES;
  const int i0 = (blockIdx.x % BMTILES) * BMROWS;
  const int tid = (int)threadIdx.x;
  const int nr = min(BMROWS, NP - i0);
  const int tile = i0 >> 4;
  const int mbase = i0 & 15;

  float tx[BMROWS], ty[BMROWS], t0c[BMROWS], t1c[BMROWS], t2c[BMROWS], Ai[BMROWS];
  #pragma unroll
  for (int r = 0; r < BMROWS; ++r) {
    int i = min(i0 + r, NP - 1);
    const float* e = PJ + (size_t)(nb * NP + i) * 8;
    tx[r] = 2.f * e[0]; ty[r] = 2.f * e[1];
    t0c[r] = 2.f * e[2]; t1c[r] = 2.f * e[3]; t2c[r] = 2.f * e[4];
    Ai[r] = e[5];
  }
  const float* pjb = PJ + (size_t)nb * NP * 8;
  uchar_t* Mb = M + (size_t)nb * M_BATCH + (size_t)tile * M_TILE;

  for (int p = tid; p < 212; p += 256) {
    const int j0 = 8 * p;
    const int kb = p >> 2, quad = p & 3;
    float xj[8], yj[8], c0j[8], c1j[8], c2j[8], Aj[8];
    #pragma unroll
    for (int e = 0; e < 8; ++e) {
      const float* q = pjb + (size_t)min(j0 + e, NP - 1) * 8;
      xj[e] = q[0]; yj[e] = q[1]; c0j[e] = q[2]; c1j[e] = q[3]; c2j[e] = q[4]; Aj[e] = q[5];
    }
    uint2 w8[BMROWS];
    for (int r = 0; r < nr; ++r) {
      float v[8];
      #pragma unroll
      for (int e = 0; e < 8; ++e) {
        float acc = Ai[r] + Aj[e];
        acc = fmaf(tx[r], xj[e], acc);
        acc = fmaf(ty[r], yj[e], acc);
        acc = fmaf(t0c[r], c0j[e], acc);
        acc = fmaf(t1c[r], c1j[e], acc);
        acc = fmaf(t2c[r], c2j[e], acc);
        float val = __builtin_amdgcn_exp2f(acc);
        int je = j0 + e;
        v[e] = (je < NP && je != i0 + r) ? val : 0.f;
      }
      uint2 wrd;
      wrd.x = __builtin_amdgcn_cvt_pk_fp8_f32(v[0], v[1], 0, false);
      wrd.x = __builtin_amdgcn_cvt_pk_fp8_f32(v[2], v[3], (int)wrd.x, true);
      wrd.y = __builtin_amdgcn_cvt_pk_fp8_f32(v[4], v[5], 0, false);
      wrd.y = __builtin_amdgcn_cvt_pk_fp8_f32(v[6], v[7], (int)wrd.y, true);
      w8[r] = wrd;
    }
    #pragma unroll
    for (int r = nr; r < BMROWS; ++r) w8[r] = make_uint2(0u, 0u);
    uchar_t* dst = Mb + (size_t)kb * 512 + (quad * 16 + mbase) * 8;
    #pragma unroll
    for (int h = 0; h < 4; ++h) {
      *(uint4*)(dst + h * 16) = make_uint4(w8[2 * h].x, w8[2 * h].y,
                                           w8[2 * h + 1].x, w8[2 * h + 1].y);
    }
  }
  __syncthreads();   // drains stores before byte fixup
  // exact Gaussian add on 5x5 neighborhood (support of exp(-8 d2))
  if (tid < nr * 25) {
    int r = tid / 25, n = tid % 25;
    int i = i0 + r;
    int dxp = n % 5 - 2, dyp = n / 5 - 2;
    int xpi = i % HH, ypi = i / HH;
    int xj2 = xpi + dxp, yj2 = ypi + dyp;
    if ((dxp | dyp) != 0 && xj2 >= 0 && xj2 < HH && yj2 >= 0 && yj2 < HH) {
      int j = yj2 * HH + xj2;
      float d2 = (float)(dxp * dxp + dyp * dyp);
      float kg = 3.f * rsg[i] * rsg[j] * __builtin_amdgcn_exp2f(-L2E8 * d2);
      const float* q = pjb + (size_t)j * 8;
      float acc = Ai[r] + q[5];
      acc = fmaf(tx[r], q[0], acc);
      acc = fmaf(ty[r], q[1], acc);
      acc = fmaf(t0c[r], q[2], acc);
      acc = fmaf(t1c[r], q[3], acc);
      acc = fmaf(t2c[r], q[4], acc);
      float val = __builtin_amdgcn_exp2f(acc) + kg;
      size_t a = (size_t)(j >> 5) * 512 + (((j >> 3) & 3) * 16 + (mbase + r)) * 8 + (j & 7);
      Mb[a] = f32_to_fp8(val);
    }
  }
}

// K7: one mean-field iteration — barrier-free fp8 MFMA streaming GEMV.
// 1 wave per block, TWO adjacent 16-row tiles (32 rows) share each B load:
// per kb: a0,a1,b0,b1 loads + 4 MFMAs. A fragment-linear (512 B coalesced).
// Grid swizzle: blockIdx = pair*16 + nb -> batch nb pinned to XCD nb%8.
__global__ __launch_bounds__(64) void k_iter(const uchar_t* __restrict__ M,
                                             const uchar_t* __restrict__ QBin,
                                             uchar_t* __restrict__ QBout,
                                             const float* __restrict__ LOGU,
                                             float* __restrict__ QF) {
  const int nb = blockIdx.x & 15;
  const int pair = blockIdx.x >> 4;         // 0..52
  const int tile0 = pair * 2;
  const int lane = (int)threadIdx.x;
  const int mrow = lane & 15, quad = lane >> 4;

  f32x4 acc00 = {0.f, 0.f, 0.f, 0.f};   // tile0, ch 0..15
  f32x4 acc01 = {0.f, 0.f, 0.f, 0.f};   // tile0, ch 16..20
  f32x4 acc10 = {0.f, 0.f, 0.f, 0.f};   // tile1, ch 0..15
  f32x4 acc11 = {0.f, 0.f, 0.f, 0.f};   // tile1, ch 16..20

  const uchar_t* Ap0 = M + (size_t)nb * M_BATCH + (size_t)tile0 * M_TILE + lane * 8;
  const uchar_t* Ap1 = Ap0 + M_TILE;
  const uchar_t* Bp = QBin + (size_t)nb * QB_BATCH + lane * 8;

  #pragma unroll 4
  for (int kb = 0; kb < NKB; ++kb) {
    long a0 = *(const long*)(Ap0);
    long a1 = *(const long*)(Ap1);
    long b0 = *(const long*)(Bp);
    long b1 = *(const long*)(Bp + 512);
    Ap0 += 512; Ap1 += 512; Bp += 1024;
    acc00 = __builtin_amdgcn_mfma_f32_16x16x32_fp8_fp8(a0, b0, acc00, 0, 0, 0);
    acc01 = __builtin_amdgcn_mfma_f32_16x16x32_fp8_fp8(a0, b1, acc01, 0, 0, 0);
    acc10 = __builtin_amdgcn_mfma_f32_16x16x32_fp8_fp8(a1, b0, acc10, 0, 0, 0);
    acc11 = __builtin_amdgcn_mfma_f32_16x16x32_fp8_fp8(a1, b1, acc11, 0, 0, 0);
  }

  const bool c1ok = (mrow + 16) < NCH;
  #pragma unroll
  for (int t = 0; t < 2; ++t) {
    const f32x4 a0v = t ? acc10 : acc00;
    const f32x4 a1v = t ? acc11 : acc01;
    const int t0 = (tile0 + t) * 16;
    #pragma unroll
    for (int reg = 0; reg < 4; ++reg) {
      int r = t0 + quad * 4 + reg;
      int rg = nb * NP + min(r, NP - 1);
      float tv0 = LOGU[(size_t)rg * QS + mrow] + a0v[reg];
      float tv1 = c1ok ? (LOGU[(size_t)rg * QS + 16 + mrow] + a1v[reg]) : -1e30f;
      float mx = fmaxf(tv0, tv1);
      mx = fmaxf(mx, __shfl_xor(mx, 1));
      mx = fmaxf(mx, __shfl_xor(mx, 2));
      mx = fmaxf(mx, __shfl_xor(mx, 4));
      mx = fmaxf(mx, __shfl_xor(mx, 8));
      float e0 = __expf(tv0 - mx);
      float e1 = c1ok ? __expf(tv1 - mx) : 0.f;
      float sm = e0 + e1;
      sm += __shfl_xor(sm, 1);
      sm += __shfl_xor(sm, 2);
      sm += __shfl_xor(sm, 4);
      sm += __shfl_xor(sm, 8);
      float rinv = 1.f / sm;
      if (r < NP) {
        int kb = r >> 5, kr = r & 31, q2 = kr >> 3, j = kr & 7;
        size_t sbo = (size_t)nb * QB_BATCH + (size_t)kb * 1024 + (q2 * 16 + mrow) * 8 + j;
        float q0 = e0 * rinv;
        QF[(size_t)(nb * NP + r) * QS + mrow] = q0;
        QBout[sbo] = f32_to_fp8(q0);
        if (c1ok) {
          float q1 = e1 * rinv;
          QF[(size_t)(nb * NP + r) * QS + 16 + mrow] = q1;
          QBout[sbo + 512] = f32_to_fp8(q1);
        }
      }
    }
  }
}

// K8: per-pixel loss contribution
__global__ void k_loss(const float* __restrict__ Qf, const float* __restrict__ P,
                       float* __restrict__ part) {
  int t = blockIdx.x * blockDim.x + threadIdx.x;
  float s = 0.f;
  if (t < NPIX) {
    const float* q = Qf + (size_t)t * QS;
    const float* p = P + (size_t)t * QS;
    float qv[NCH];
    float qsum = 0.f;
    #pragma unroll
    for (int c = 0; c < NCH; ++c) { qv[c] = fmaxf(q[c], EPSV); qsum += qv[c]; }
    float r = 1.f / qsum;
    #pragma unroll
    for (int c = 0; c < NCH; ++c) {
      float qs = qv[c] * r;
      float ratio = fminf(fmaxf(qs / p[c], 0.05f), 20.0f);
      s += qs * logf(ratio);
    }
  }
  __shared__ float red[256];
  red[threadIdx.x] = s;
  __syncthreads();
  for (int st = 128; st > 0; st >>= 1) {
    if ((int)threadIdx.x < st) red[threadIdx.x] += red[threadIdx.x + st];
    __syncthreads();
  }
  if (threadIdx.x == 0) part[blockIdx.x] = red[0];
}

// K9: final reduction -> d_out[0]
__global__ void k_final(const float* __restrict__ part, float* __restrict__ out) {
  float s = 0.f;
  for (int k = threadIdx.x; k < LOSS_BLOCKS; k += 64) s += part[k];
  s = wave_sum(s);
  if (threadIdx.x == 0) out[0] = s / (float)NPIX;
}

}  // namespace

extern "C" void kernel_launch(void* const* d_in, const int* in_sizes, int n_in,
                              void* d_out, int out_size, void* d_ws, size_t ws_size,
                              hipStream_t stream) {
  const float* images  = (const float*)d_in[0];   // (16,3,321,321) fp32
  const float* predict = (const float*)d_in[1];   // (16,21,41,41) fp32
  float* out = (float*)d_out;
  float* ws = (float*)d_ws;

  float*  W    = ws + OFF_W;
  float*  RX   = ws + OFF_RX;
  float4* COL  = (float4*)(ws + OFF_COL);
  float*  P    = ws + OFF_P;
  float*  LOGU = ws + OFF_LOGU;
  float*  QF   = ws + OFF_QF;
  float*  RSG  = ws + OFF_RSG;
  float2* XY   = (float2*)(ws + OFF_XY);
  float*  PART = ws + OFF_PART;
  float*  PJ   = ws + OFF_PJ;
  uchar_t* QB_A = (uchar_t*)(ws + OFF_QB);
  uchar_t* QB_B = QB_A + (size_t)QB_BUF;
  uchar_t* M    = (uchar_t*)(ws + OFF_M);

  hipLaunchKernelGGL(k_zero, dim3((unsigned)((QB_ZERO_DWORDS + 255) / 256)), dim3(256), 0,
                     stream, (uint_t*)QB_A);
  hipLaunchKernelGGL(k_weights, dim3(1), dim3(64), 0, stream, W);
  hipLaunchKernelGGL(k_xy, dim3((NP + 255) / 256), dim3(256), 0, stream, XY);
  hipLaunchKernelGGL(k_resize_x, dim3((RXN + 255) / 256), dim3(256), 0, stream, images, W, RX);
  hipLaunchKernelGGL(k_resize_y, dim3(LOSS_BLOCKS), dim3(256), 0, stream, RX, W, (float*)COL);
  hipLaunchKernelGGL(k_probs, dim3(LOSS_BLOCKS), dim3(256), 0, stream, predict, P, LOGU, QB_A);
  hipLaunchKernelGGL(k_rsg, dim3(NP), dim3(64), 0, stream, RSG);
  hipLaunchKernelGGL(k_rsb, dim3(NBATCH * RSB_TILES), dim3(512), 0, stream, COL, XY);
  hipLaunchKernelGGL(k_prep, dim3(LOSS_BLOCKS), dim3(256), 0, stream, COL, XY, PJ);
  hipLaunchKernelGGL(k_buildM, dim3(NBATCH * BMTILES), dim3(256), 0, stream, PJ, RSG, M);

  const uchar_t* qbin = QB_A;
  uchar_t* qbout = QB_B;
  for (int it = 0; it < 10; ++it) {
    hipLaunchKernelGGL(k_iter, dim3(NPAIR * NBATCH), dim3(64), 0, stream,
                       M, qbin, qbout, LOGU, QF);
    const uchar_t* t = qbout; qbout = (uchar_t*)qbin; qbin = t;
  }
  hipLaunchKernelGGL(k_loss, dim3(LOSS_BLOCKS), dim3(256), 0, stream, QF, P, PART);
  hipLaunchKernelGGL(k_final, dim3(1), dim3(64), 0, stream, PART, out);
}